// Round 1
// 170.710 us; speedup vs baseline: 1.0015x; 1.0015x over previous
//
#include <hip/hip_runtime.h>
#include <hip/hip_bf16.h>
#include <stdint.h>

// Problem constants: B=2, H=16, S=2048, D=64, fp32 in/out.
#define BB 2
#define HH 16
#define SS 2048
#define DD 64
constexpr int BH = BB * HH;
constexpr int NT = SS / 64;    // 32 K-tiles
constexpr int QB = 16;         // q-tiles of 128 => 16 blocks per bh

typedef _Float16 f16_t;
typedef f16_t f16x8 __attribute__((ext_vector_type(8)));
typedef float f32x4 __attribute__((ext_vector_type(4)));

__device__ __forceinline__ uint32_t pkf16(float a, float b) {
    // two fp32 -> packed f16x2 (v_cvt_pkrtz_f16_f32), as raw dword
    return __builtin_bit_cast(uint32_t, __builtin_amdgcn_cvt_pkrtz(a, b));
}

// =====================================================================
// Pre-pass: pack K -> f16 tiles [64 key][64 d], and V^T·mask -> f16 tiles
// [64 d][64 key], per (bh, kt).  Each row's eight 16B chunks are XOR-
// swizzled (chunk j -> j ^ (row&7)) IN GLOBAL MEMORY so the main kernel's
// linear global_load_lds image is already bank-conflict-free for the
// ds_read_b128 fragment reads (linear LDS dest + pre-swizzled source +
// swizzle-on-read; the XOR is an involution).
// =====================================================================
__global__ __launch_bounds__(256)
void prepack(const float* __restrict__ Kg, const float* __restrict__ Vg,
             const float* __restrict__ Mg, f16_t* __restrict__ Kp,
             f16_t* __restrict__ Vp)
{
    __shared__ float Vs[64][65];          // fp32 V tile staging (+1 pad)
    const int bh = blockIdx.x % BH;
    const int kt = blockIdx.x / BH;
    const int b  = bh / HH;
    const int t  = threadIdx.x;
    const size_t gbase = (size_t)bh * SS * DD + (size_t)kt * 64 * DD;
    const size_t tbase = ((size_t)bh * NT + kt) * 4096;   // f16 elements

    // ---- K: 512 chunks of 16B (8 f16) ----
    for (int c = t; c < 512; c += 256) {
        const int row = c >> 3, j = c & 7;
        const float* kp = Kg + gbase + (size_t)row * DD + j * 8;
        float4 a = *(const float4*)kp;
        float4 d = *(const float4*)(kp + 4);
        uint4 w = make_uint4(pkf16(a.x, a.y), pkf16(a.z, a.w),
                             pkf16(d.x, d.y), pkf16(d.z, d.w));
        *(uint4*)&Kp[tbase + (size_t)row * 64 + ((j ^ (row & 7)) * 8)] = w;
    }

    // ---- V: coalesced fp32 load, mask fold, into LDS [key][d] ----
    for (int c = t; c < 1024; c += 256) {
        const int key = c >> 4, dc = (c & 15) * 4;
        float4 v = *(const float4*)(Vg + gbase + (size_t)key * DD + dc);
        const float m = Mg[(size_t)b * SS + kt * 64 + key];
        Vs[key][dc + 0] = v.x * m;
        Vs[key][dc + 1] = v.y * m;
        Vs[key][dc + 2] = v.z * m;
        Vs[key][dc + 3] = v.w * m;
    }
    __syncthreads();

    // ---- V^T: 512 chunks of 16B, transposed out of LDS ----
    for (int c = t; c < 512; c += 256) {
        const int dr = c >> 3, j = c & 7;
        float v0 = Vs[j * 8 + 0][dr], v1 = Vs[j * 8 + 1][dr];
        float v2 = Vs[j * 8 + 2][dr], v3 = Vs[j * 8 + 3][dr];
        float v4 = Vs[j * 8 + 4][dr], v5 = Vs[j * 8 + 5][dr];
        float v6 = Vs[j * 8 + 6][dr], v7 = Vs[j * 8 + 7][dr];
        uint4 w = make_uint4(pkf16(v0, v1), pkf16(v2, v3),
                             pkf16(v4, v5), pkf16(v6, v7));
        *(uint4*)&Vp[tbase + (size_t)dr * 64 + ((j ^ (dr & 7)) * 8)] = w;
    }
}

// =====================================================================
// Main kernel: flash attention over prepacked f16 tiles.  Staging is pure
// DMA (global_load_lds dwordx4, no VALU, no VGPR round-trip), double-
// buffered with a one-tile prefetch kept in flight across raw s_barriers
// via counted s_waitcnt vmcnt(2).
// =====================================================================
__global__ __launch_bounds__(512)
void fattn7(const float* __restrict__ Qg, const f16_t* __restrict__ Kp,
            const f16_t* __restrict__ Vp, const float* __restrict__ Sg,
            float* __restrict__ Og)
{
    __shared__ __align__(16) f16_t Kt[2][4096];          // 8KB per buffer
    __shared__ __align__(16) f16_t Vt[2][4096];
    __shared__ __align__(16) f16_t Pt[8][16][72];        // per-wave P^T

    const int bh   = blockIdx.x % BH;      // bh-minor => XCD affinity
    const int qt   = blockIdx.x / BH;
    const int b    = bh / HH;
    const int tid  = threadIdx.x;
    const int wave = tid >> 6;
    const int lane = tid & 63;
    const int l16  = lane & 15;
    const int quad = lane >> 4;

    const float sc = Sg[b] * 1.44269504088896340736f;  // scale*log2e into Q
    const size_t base = (size_t)bh * SS * DD;
    const size_t tb0  = (size_t)bh * NT * 4096;        // f16 elems
    const int q0 = qt * 128 + wave * 16;

    // DMA-stage tile kt into LDS buffer buf: each thread one 16B chunk of K
    // and one of V.  LDS dest is wave-uniform base + lane*16 (linear image).
    auto stage = [&](int kt, int buf) {
        const f16_t* ks = Kp + tb0 + (size_t)kt * 4096 + tid * 8;
        const f16_t* vs = Vp + tb0 + (size_t)kt * 4096 + tid * 8;
        __builtin_amdgcn_global_load_lds(
            (const __attribute__((address_space(1))) void*)ks,
            (__attribute__((address_space(3))) void*)&Kt[buf][wave * 512],
            16, 0, 0);
        __builtin_amdgcn_global_load_lds(
            (const __attribute__((address_space(1))) void*)vs,
            (__attribute__((address_space(3))) void*)&Vt[buf][wave * 512],
            16, 0, 0);
    };

    stage(0, 0);   // prefetch tile 0 before anything else

    // ---- Q fragments (B-operand layout), fp16 of (q * sc) ----
    f16x8 qf[2];
    {
        const float* qp = Qg + base + (size_t)(q0 + l16) * DD + quad * 8;
#pragma unroll
        for (int kc = 0; kc < 2; ++kc) {
            float4 a  = *(const float4*)(qp + kc * 32);
            float4 b4 = *(const float4*)(qp + kc * 32 + 4);
            f16x8 f;
            f[0] = (f16_t)(a.x * sc);  f[1] = (f16_t)(a.y * sc);
            f[2] = (f16_t)(a.z * sc);  f[3] = (f16_t)(a.w * sc);
            f[4] = (f16_t)(b4.x * sc); f[5] = (f16_t)(b4.y * sc);
            f[6] = (f16_t)(b4.z * sc); f[7] = (f16_t)(b4.w * sc);
            qf[kc] = f;
        }
    }

    f32x4 Ot[4];                // O^T: D[m=d=mt*16+quad*4+r][n=q=l16]
#pragma unroll
    for (int mt = 0; mt < 4; ++mt) Ot[mt] = f32x4{0.f, 0.f, 0.f, 0.f};
    float m_run = -1e30f, l_run = 0.0f;

    const int swz = (l16 & 7) << 3;   // f16-index XOR within a 64-elem row

    for (int kt = 0; kt < NT; ++kt) {
        const int cur = kt & 1;
        if (kt + 1 < NT) {
            stage(kt + 1, cur ^ 1);                   // prefetch next tile
            asm volatile("s_waitcnt vmcnt(2)" ::: "memory");  // tile kt done
        } else {
            asm volatile("s_waitcnt vmcnt(0)" ::: "memory");
        }
        __builtin_amdgcn_s_barrier();   // tile kt visible to all waves

        // ---- S^T = K Q^T ----
        f32x4 Sfr[4];
#pragma unroll
        for (int mt = 0; mt < 4; ++mt) {
            f32x4 acc = f32x4{0.f, 0.f, 0.f, 0.f};
#pragma unroll
            for (int kc = 0; kc < 2; ++kc) {
                const int off = (mt * 16 + l16) * 64 + ((kc * 32 + quad * 8) ^ swz);
                f16x8 kh = *(const f16x8*)&Kt[cur][off];
                acc = __builtin_amdgcn_mfma_f32_16x16x32_f16(kh, qf[kc], acc, 0, 0, 0);
            }
            Sfr[mt] = acc;   // D[m=key][n=q=l16], pre-scaled (sc in Q)
        }

        // ---- Online softmax: 16 in-lane values (q = l16) ----
        float m0 = fmaxf(fmaxf(Sfr[0][0], Sfr[0][1]), fmaxf(Sfr[0][2], Sfr[0][3]));
        float m1 = fmaxf(fmaxf(Sfr[1][0], Sfr[1][1]), fmaxf(Sfr[1][2], Sfr[1][3]));
        float m2 = fmaxf(fmaxf(Sfr[2][0], Sfr[2][1]), fmaxf(Sfr[2][2], Sfr[2][3]));
        float m3 = fmaxf(fmaxf(Sfr[3][0], Sfr[3][1]), fmaxf(Sfr[3][2], Sfr[3][3]));
        float mx = fmaxf(fmaxf(m0, m1), fmaxf(m2, m3));
        mx = fmaxf(mx, __shfl_xor(mx, 16));
        mx = fmaxf(mx, __shfl_xor(mx, 32));

        if (__any(mx > m_run)) {
            const float mnew  = fmaxf(m_run, mx);
            const float alpha = exp2f(m_run - mnew);
            m_run = mnew;
            l_run *= alpha;
#pragma unroll
            for (int mt = 0; mt < 4; ++mt) Ot[mt] *= alpha;
        }

        float ps[4][4];
        float rs = 0.0f;
#pragma unroll
        for (int mt = 0; mt < 4; ++mt)
#pragma unroll
            for (int r = 0; r < 4; ++r) {
                ps[mt][r] = exp2f(Sfr[mt][r] - m_run);
                rs += ps[mt][r];
            }
        rs += __shfl_xor(rs, 16);
        rs += __shfl_xor(rs, 32);
        l_run += rs;

        // ---- P^T -> LDS: packed f16 pairs, 4x ds_write_b64 ----
#pragma unroll
        for (int mt = 0; mt < 4; ++mt) {
            uint2 w = make_uint2(pkf16(ps[mt][0], ps[mt][1]),
                                 pkf16(ps[mt][2], ps[mt][3]));
            *(uint2*)&Pt[wave][l16][mt * 16 + quad * 4] = w;
        }
        // Pt is per-wave private; in-wave RAW handled by lgkmcnt.

        // ---- O^T += V^T P^T  (V already mask-folded in prepack) ----
#pragma unroll
        for (int kc = 0; kc < 2; ++kc) {
            f16x8 pf = *(const f16x8*)&Pt[wave][l16][kc * 32 + quad * 8];
#pragma unroll
            for (int mt = 0; mt < 4; ++mt) {
                const int off = (mt * 16 + l16) * 64 + ((kc * 32 + quad * 8) ^ swz);
                f16x8 vf = *(const f16x8*)&Vt[cur][off];
                Ot[mt] = __builtin_amdgcn_mfma_f32_16x16x32_f16(vf, pf, Ot[mt], 0, 0, 0);
            }
        }
        __builtin_amdgcn_s_barrier();   // reads of buf[cur] done before reuse
    }

    // ---- Epilogue: O[q][d] = O^T[d][q] / l ----
    const float inv = 1.0f / l_run;
    float* op = Og + base + (size_t)(q0 + l16) * DD + quad * 4;
#pragma unroll
    for (int mt = 0; mt < 4; ++mt) {
#pragma unroll
        for (int r = 0; r < 4; ++r)
            op[mt * 16 + r] = Ot[mt][r] * inv;
    }
}

// =====================================================================
// Fallback (no/short workspace): previous known-good fused kernel.
// =====================================================================
__global__ __launch_bounds__(512)
void fattn6(const float* __restrict__ Qg, const float* __restrict__ Kg,
            const float* __restrict__ Vg, const float* __restrict__ Mg,
            const float* __restrict__ Sg, float* __restrict__ Og)
{
    __shared__ __align__(16) f16_t Kh_lds[64][72];
    __shared__ __align__(16) f16_t Vt_lds[64][72];
    __shared__ __align__(16) f16_t Pt_lds[8][16][72];
    __shared__ float msk_lds[SS];

    const int bh   = blockIdx.x % BH;
    const int qt   = blockIdx.x / BH;
    const int b    = bh / HH;
    const int tid  = threadIdx.x;
    const int wave = tid >> 6;
    const int lane = tid & 63;
    const int l16  = lane & 15;
    const int quad = lane >> 4;

    const float sc = Sg[b] * 1.44269504088896340736f;
    const size_t base = (size_t)bh * SS * DD;
    const int q0 = qt * 128 + wave * 16;

    for (int i = tid; i < SS; i += 512) msk_lds[i] = Mg[(size_t)b * SS + i];

    f16x8 qf[2];
    {
        const float* qp = Qg + base + (size_t)(q0 + l16) * DD + quad * 8;
#pragma unroll
        for (int kc = 0; kc < 2; ++kc) {
            float4 a  = *(const float4*)(qp + kc * 32);
            float4 b4 = *(const float4*)(qp + kc * 32 + 4);
            f16x8 f;
            f[0] = (f16_t)(a.x * sc);  f[1] = (f16_t)(a.y * sc);
            f[2] = (f16_t)(a.z * sc);  f[3] = (f16_t)(a.w * sc);
            f[4] = (f16_t)(b4.x * sc); f[5] = (f16_t)(b4.y * sc);
            f[6] = (f16_t)(b4.z * sc); f[7] = (f16_t)(b4.w * sc);
            qf[kc] = f;
        }
    }

    f32x4 Ot[4];
#pragma unroll
    for (int mt = 0; mt < 4; ++mt) Ot[mt] = f32x4{0.f, 0.f, 0.f, 0.f};
    float m_run = -1e30f, l_run = 0.0f;

    const int krow = tid >> 3;
    const int kc8  = (tid & 7) * 8;
    const int vd   = tid & 63;
    const int vk0  = (tid >> 6) * 8;

    for (int kt = 0; kt < NT; ++kt) {
        __syncthreads();
        {
            const float* kp = Kg + base + (size_t)(kt * 64 + krow) * DD + kc8;
            float4 a0 = *(const float4*)(kp);
            float4 a1 = *(const float4*)(kp + 4);
            uint4 w = make_uint4(pkf16(a0.x, a0.y), pkf16(a0.z, a0.w),
                                 pkf16(a1.x, a1.y), pkf16(a1.z, a1.w));
            *(uint4*)&Kh_lds[krow][kc8] = w;
        }
        {
            const float* vp = Vg + base + (size_t)(kt * 64 + vk0) * DD + vd;
            const float* mp = &msk_lds[kt * 64 + vk0];
            float v0 = vp[0 * DD] * mp[0], v1 = vp[1 * DD] * mp[1];
            float v2 = vp[2 * DD] * mp[2], v3 = vp[3 * DD] * mp[3];
            float v4 = vp[4 * DD] * mp[4], v5 = vp[5 * DD] * mp[5];
            float v6 = vp[6 * DD] * mp[6], v7 = vp[7 * DD] * mp[7];
            uint4 w = make_uint4(pkf16(v0, v1), pkf16(v2, v3),
                                 pkf16(v4, v5), pkf16(v6, v7));
            *(uint4*)&Vt_lds[vd][vk0] = w;
        }
        __syncthreads();

        f32x4 Sfr[4];
#pragma unroll
        for (int mt = 0; mt < 4; ++mt) {
            f32x4 acc = f32x4{0.f, 0.f, 0.f, 0.f};
#pragma unroll
            for (int kc = 0; kc < 2; ++kc) {
                f16x8 kh = *(const f16x8*)&Kh_lds[mt * 16 + l16][kc * 32 + quad * 8];
                acc = __builtin_amdgcn_mfma_f32_16x16x32_f16(kh, qf[kc], acc, 0, 0, 0);
            }
            Sfr[mt] = acc;
        }

        float mx = Sfr[0][0];
#pragma unroll
        for (int mt = 0; mt < 4; ++mt)
#pragma unroll
            for (int r = 0; r < 4; ++r) mx = fmaxf(mx, Sfr[mt][r]);
        mx = fmaxf(mx, __shfl_xor(mx, 16));
        mx = fmaxf(mx, __shfl_xor(mx, 32));

        if (__any(mx > m_run)) {
            const float mnew  = fmaxf(m_run, mx);
            const float alpha = exp2f(m_run - mnew);
            m_run = mnew;
            l_run *= alpha;
#pragma unroll
            for (int mt = 0; mt < 4; ++mt) Ot[mt] *= alpha;
        }

        float ps[4][4];
        float rs = 0.0f;
#pragma unroll
        for (int mt = 0; mt < 4; ++mt)
#pragma unroll
            for (int r = 0; r < 4; ++r) {
                ps[mt][r] = exp2f(Sfr[mt][r] - m_run);
                rs += ps[mt][r];
            }
        rs += __shfl_xor(rs, 16);
        rs += __shfl_xor(rs, 32);
        l_run += rs;

#pragma unroll
        for (int mt = 0; mt < 4; ++mt) {
            uint2 w = make_uint2(pkf16(ps[mt][0], ps[mt][1]),
                                 pkf16(ps[mt][2], ps[mt][3]));
            *(uint2*)&Pt_lds[wave][l16][mt * 16 + quad * 4] = w;
        }

#pragma unroll
        for (int kc = 0; kc < 2; ++kc) {
            f16x8 pf = *(const f16x8*)&Pt_lds[wave][l16][kc * 32 + quad * 8];
#pragma unroll
            for (int mt = 0; mt < 4; ++mt) {
                f16x8 vf = *(const f16x8*)&Vt_lds[mt * 16 + l16][kc * 32 + quad * 8];
                Ot[mt] = __builtin_amdgcn_mfma_f32_16x16x32_f16(vf, pf, Ot[mt], 0, 0, 0);
            }
        }
    }

    const float inv = 1.0f / l_run;
    float* op = Og + base + (size_t)(q0 + l16) * DD + quad * 4;
#pragma unroll
    for (int mt = 0; mt < 4; ++mt) {
#pragma unroll
        for (int r = 0; r < 4; ++r)
            op[mt * 16 + r] = Ot[mt][r] * inv;
    }
}

extern "C" void kernel_launch(void* const* d_in, const int* in_sizes, int n_in,
                              void* d_out, int out_size, void* d_ws, size_t ws_size,
                              hipStream_t stream) {
    const float* Qg = (const float*)d_in[0];
    const float* Kg = (const float*)d_in[1];
    const float* Vg = (const float*)d_in[2];
    // d_in[3] = query_mask (all ones, unused by reference)
    const float* Mg = (const float*)d_in[4];  // key_mask [B,1,1,S]
    const float* Sg = (const float*)d_in[5];  // scale_factor [B,1,1,1]
    // d_in[6] = dropout (0, identity)
    float* Og = (float*)d_out;

    const size_t kv_elems = (size_t)BH * SS * DD;          // per array, f16
    const size_t need = 2 * kv_elems * sizeof(f16_t);      // 16.8 MB

    if (d_ws != nullptr && ws_size >= need) {
        f16_t* Kp = (f16_t*)d_ws;
        f16_t* Vp = Kp + kv_elems;
        prepack<<<dim3(BH * NT), dim3(256), 0, stream>>>(Kg, Vg, Mg, Kp, Vp);
        fattn7<<<dim3(BH * QB), dim3(512), 0, stream>>>(Qg, Kp, Vp, Sg, Og);
    } else {
        fattn6<<<dim3(BH * QB), dim3(512), 0, stream>>>(Qg, Kg, Vg, Mg, Sg, Og);
    }
}

// Round 2
// 154.652 us; speedup vs baseline: 1.1055x; 1.1038x over previous
//
#include <hip/hip_runtime.h>
#include <hip/hip_bf16.h>
#include <stdint.h>

// Problem constants: B=2, H=16, S=2048, D=64, fp32 in/out.
#define BB 2
#define HH 16
#define SS 2048
#define DD 64
constexpr int BH = BB * HH;
constexpr int NT = SS / 64;    // 32 K-tiles
constexpr int QB = 16;         // q-tiles of 128 => 16 blocks per bh

typedef _Float16 f16_t;
typedef f16_t f16x8 __attribute__((ext_vector_type(8)));
typedef float f32x4 __attribute__((ext_vector_type(4)));

__device__ __forceinline__ uint32_t pkf16(float a, float b) {
    // two fp32 -> packed f16x2 (v_cvt_pkrtz_f16_f32), as raw dword
    return __builtin_bit_cast(uint32_t, __builtin_amdgcn_cvt_pkrtz(a, b));
}

// =====================================================================
// Pre-pass: pack K -> f16 tiles [64 key][64 d], and V^T·mask -> f16 tiles
// [64 d][64 key], per (bh, kt).  Each row's eight 16B chunks are XOR-
// swizzled (chunk j -> j ^ (row&7)) IN GLOBAL MEMORY so the main kernel's
// linear global_load_lds image is already bank-conflict-free for the
// ds_read_b128 fragment reads.
// =====================================================================
__global__ __launch_bounds__(256)
void prepack(const float* __restrict__ Kg, const float* __restrict__ Vg,
             const float* __restrict__ Mg, f16_t* __restrict__ Kp,
             f16_t* __restrict__ Vp)
{
    __shared__ float Vs[64][65];          // fp32 V tile staging (+1 pad)
    const int bh = blockIdx.x % BH;
    const int kt = blockIdx.x / BH;
    const int b  = bh / HH;
    const int t  = threadIdx.x;
    const size_t gbase = (size_t)bh * SS * DD + (size_t)kt * 64 * DD;
    const size_t tbase = ((size_t)bh * NT + kt) * 4096;   // f16 elements

    // ---- K: 512 chunks of 16B (8 f16) ----
    for (int c = t; c < 512; c += 256) {
        const int row = c >> 3, j = c & 7;
        const float* kp = Kg + gbase + (size_t)row * DD + j * 8;
        float4 a = *(const float4*)kp;
        float4 d = *(const float4*)(kp + 4);
        uint4 w = make_uint4(pkf16(a.x, a.y), pkf16(a.z, a.w),
                             pkf16(d.x, d.y), pkf16(d.z, d.w));
        *(uint4*)&Kp[tbase + (size_t)row * 64 + ((j ^ (row & 7)) * 8)] = w;
    }

    // ---- V: coalesced fp32 load, mask fold, into LDS [key][d] ----
    for (int c = t; c < 1024; c += 256) {
        const int key = c >> 4, dc = (c & 15) * 4;
        float4 v = *(const float4*)(Vg + gbase + (size_t)key * DD + dc);
        const float m = Mg[(size_t)b * SS + kt * 64 + key];
        Vs[key][dc + 0] = v.x * m;
        Vs[key][dc + 1] = v.y * m;
        Vs[key][dc + 2] = v.z * m;
        Vs[key][dc + 3] = v.w * m;
    }
    __syncthreads();

    // ---- V^T: 512 chunks of 16B, transposed out of LDS ----
    for (int c = t; c < 512; c += 256) {
        const int dr = c >> 3, j = c & 7;
        float v0 = Vs[j * 8 + 0][dr], v1 = Vs[j * 8 + 1][dr];
        float v2 = Vs[j * 8 + 2][dr], v3 = Vs[j * 8 + 3][dr];
        float v4 = Vs[j * 8 + 4][dr], v5 = Vs[j * 8 + 5][dr];
        float v6 = Vs[j * 8 + 6][dr], v7 = Vs[j * 8 + 7][dr];
        uint4 w = make_uint4(pkf16(v0, v1), pkf16(v2, v3),
                             pkf16(v4, v5), pkf16(v6, v7));
        *(uint4*)&Vp[tbase + (size_t)dr * 64 + ((j ^ (dr & 7)) * 8)] = w;
    }
}

// =====================================================================
// Main kernel: flash attention over prepacked f16 tiles.
// - DMA staging (global_load_lds dwordx4), K double-buffered, V TRIPLE-
//   buffered: iter kt computes S(kt) and PV(kt-1), so PV MFMAs no longer
//   depend on this iteration's softmax -> MFMA/VALU pipes overlap.
// - s_setprio(1) around the merged MFMA cluster (role diversity now
//   exists across waves).
// - Defer-max rescale (THR=8): O-rescale fires only when the running max
//   is exceeded by >8 (rare with random data); P bounded by 2^8.
// - exp2 via raw v_exp_f32 builtin; max3-friendly reduction trees.
// =====================================================================
__global__ __launch_bounds__(512)
void fattn8(const float* __restrict__ Qg, const f16_t* __restrict__ Kp,
            const f16_t* __restrict__ Vp, const float* __restrict__ Sg,
            float* __restrict__ Og)
{
    __shared__ __align__(16) f16_t Kt[2][4096];          // 8KB per buffer
    __shared__ __align__(16) f16_t Vt[3][4096];          // triple buffer
    __shared__ __align__(16) f16_t Pt[8][16][72];        // per-wave P^T

    const int bh   = blockIdx.x % BH;      // bh-minor => XCD affinity
    const int qt   = blockIdx.x / BH;
    const int b    = bh / HH;
    const int tid  = threadIdx.x;
    const int wave = tid >> 6;
    const int lane = tid & 63;
    const int l16  = lane & 15;
    const int quad = lane >> 4;

    const float sc = Sg[b] * 1.44269504088896340736f;  // scale*log2e into Q
    const size_t base = (size_t)bh * SS * DD;
    const size_t tb0  = (size_t)bh * NT * 4096;        // f16 elems
    const int q0 = qt * 128 + wave * 16;

    // DMA-stage tile kt: each thread one 16B chunk of K and one of V.
    auto stage = [&](int kt, int kbuf, int vbuf) {
        const f16_t* ks = Kp + tb0 + (size_t)kt * 4096 + tid * 8;
        const f16_t* vs = Vp + tb0 + (size_t)kt * 4096 + tid * 8;
        __builtin_amdgcn_global_load_lds(
            (const __attribute__((address_space(1))) void*)ks,
            (__attribute__((address_space(3))) void*)&Kt[kbuf][wave * 512],
            16, 0, 0);
        __builtin_amdgcn_global_load_lds(
            (const __attribute__((address_space(1))) void*)vs,
            (__attribute__((address_space(3))) void*)&Vt[vbuf][wave * 512],
            16, 0, 0);
    };

    stage(0, 0, 0);   // prefetch tile 0 before anything else

    // ---- Q fragments (B-operand layout), fp16 of (q * sc) ----
    f16x8 qf[2];
    {
        const float* qp = Qg + base + (size_t)(q0 + l16) * DD + quad * 8;
#pragma unroll
        for (int kc = 0; kc < 2; ++kc) {
            float4 a  = *(const float4*)(qp + kc * 32);
            float4 b4 = *(const float4*)(qp + kc * 32 + 4);
            f16x8 f;
            f[0] = (f16_t)(a.x * sc);  f[1] = (f16_t)(a.y * sc);
            f[2] = (f16_t)(a.z * sc);  f[3] = (f16_t)(a.w * sc);
            f[4] = (f16_t)(b4.x * sc); f[5] = (f16_t)(b4.y * sc);
            f[6] = (f16_t)(b4.z * sc); f[7] = (f16_t)(b4.w * sc);
            qf[kc] = f;
        }
    }

    f32x4 Ot[4];                // O^T: D[m=d=mt*16+quad*4+r][n=q=l16]
#pragma unroll
    for (int mt = 0; mt < 4; ++mt) Ot[mt] = f32x4{0.f, 0.f, 0.f, 0.f};
    float m_run = -1e30f, l_run = 0.0f;

    const int swz = (l16 & 7) << 3;   // f16-index XOR within a 64-elem row

    int vcur = 0;                     // kt % 3
    for (int kt = 0; kt < NT; ++kt) {
        const int kcur = kt & 1;
        const int vnxt = (vcur == 2) ? 0 : vcur + 1;
        if (kt + 1 < NT) {
            stage(kt + 1, kcur ^ 1, vnxt);            // prefetch next tile
            asm volatile("s_waitcnt vmcnt(2)" ::: "memory");  // tile kt done
        } else {
            asm volatile("s_waitcnt vmcnt(0)" ::: "memory");
        }
        __builtin_amdgcn_s_barrier();   // tile kt visible to all waves

        __builtin_amdgcn_s_setprio(1);
        // ---- S^T = K Q^T  (tile kt) ----
        f32x4 Sfr[4];
#pragma unroll
        for (int mt = 0; mt < 4; ++mt) {
            f32x4 acc = f32x4{0.f, 0.f, 0.f, 0.f};
#pragma unroll
            for (int kc = 0; kc < 2; ++kc) {
                const int off = (mt * 16 + l16) * 64 + ((kc * 32 + quad * 8) ^ swz);
                f16x8 kh = *(const f16x8*)&Kt[kcur][off];
                acc = __builtin_amdgcn_mfma_f32_16x16x32_f16(kh, qf[kc], acc, 0, 0, 0);
            }
            Sfr[mt] = acc;   // D[m=key][n=q=l16], pre-scaled (sc in Q)
        }

        // ---- O^T += V^T(kt-1) P^T(kt-1): independent of this softmax ----
        if (kt > 0) {
            const int vprv = (vcur == 0) ? 2 : vcur - 1;
#pragma unroll
            for (int kc = 0; kc < 2; ++kc) {
                f16x8 pf = *(const f16x8*)&Pt[wave][l16][kc * 32 + quad * 8];
#pragma unroll
                for (int mt = 0; mt < 4; ++mt) {
                    const int off = (mt * 16 + l16) * 64 + ((kc * 32 + quad * 8) ^ swz);
                    f16x8 vf = *(const f16x8*)&Vt[vprv][off];
                    Ot[mt] = __builtin_amdgcn_mfma_f32_16x16x32_f16(vf, pf, Ot[mt], 0, 0, 0);
                }
            }
        }
        __builtin_amdgcn_s_setprio(0);

        // ---- Online softmax (tile kt): 16 in-lane values (q = l16) ----
        float a0 = fmaxf(fmaxf(Sfr[0][0], Sfr[0][1]), Sfr[0][2]);
        float b0 = fmaxf(fmaxf(Sfr[1][0], Sfr[1][1]), Sfr[1][2]);
        a0 = fmaxf(fmaxf(a0, Sfr[0][3]), Sfr[2][0]);
        b0 = fmaxf(fmaxf(b0, Sfr[1][3]), Sfr[2][1]);
        a0 = fmaxf(fmaxf(a0, Sfr[2][2]), Sfr[3][0]);
        b0 = fmaxf(fmaxf(b0, Sfr[2][3]), Sfr[3][1]);
        a0 = fmaxf(fmaxf(a0, Sfr[3][2]), Sfr[3][3]);
        float mx = fmaxf(a0, b0);
        mx = fmaxf(mx, __shfl_xor(mx, 16));
        mx = fmaxf(mx, __shfl_xor(mx, 32));

        // Defer-max: only rescale when old max exceeded by >8 (P <= 2^8).
        if (__any(mx > m_run + 8.0f)) {
            const float mnew  = fmaxf(m_run, mx);
            const float alpha = __builtin_amdgcn_exp2f(m_run - mnew);
            m_run = mnew;
            l_run *= alpha;
#pragma unroll
            for (int mt = 0; mt < 4; ++mt) Ot[mt] *= alpha;
        }

        float ps[4][4];
#pragma unroll
        for (int mt = 0; mt < 4; ++mt)
#pragma unroll
            for (int r = 0; r < 4; ++r)
                ps[mt][r] = __builtin_amdgcn_exp2f(Sfr[mt][r] - m_run);

        // pairwise sum tree
        float s0 = (ps[0][0] + ps[0][1]) + (ps[0][2] + ps[0][3]);
        float s1 = (ps[1][0] + ps[1][1]) + (ps[1][2] + ps[1][3]);
        float s2 = (ps[2][0] + ps[2][1]) + (ps[2][2] + ps[2][3]);
        float s3 = (ps[3][0] + ps[3][1]) + (ps[3][2] + ps[3][3]);
        float rs = (s0 + s1) + (s2 + s3);
        rs += __shfl_xor(rs, 16);
        rs += __shfl_xor(rs, 32);
        l_run += rs;

        // ---- P^T(kt) -> LDS (read by PV next iteration; same wave) ----
#pragma unroll
        for (int mt = 0; mt < 4; ++mt) {
            uint2 w = make_uint2(pkf16(ps[mt][0], ps[mt][1]),
                                 pkf16(ps[mt][2], ps[mt][3]));
            *(uint2*)&Pt[wave][l16][mt * 16 + quad * 4] = w;
        }

        __builtin_amdgcn_s_barrier();   // reads of K[kcur]/V[vprv] done
        vcur = vnxt;
    }

    // ---- Drain: PV(NT-1) ----
    {
        const int vprv = (vcur == 0) ? 2 : vcur - 1;   // (NT-1) % 3
#pragma unroll
        for (int kc = 0; kc < 2; ++kc) {
            f16x8 pf = *(const f16x8*)&Pt[wave][l16][kc * 32 + quad * 8];
#pragma unroll
            for (int mt = 0; mt < 4; ++mt) {
                const int off = (mt * 16 + l16) * 64 + ((kc * 32 + quad * 8) ^ swz);
                f16x8 vf = *(const f16x8*)&Vt[vprv][off];
                Ot[mt] = __builtin_amdgcn_mfma_f32_16x16x32_f16(vf, pf, Ot[mt], 0, 0, 0);
            }
        }
    }

    // ---- Epilogue: O[q][d] = O^T[d][q] / l ----
    const float inv = 1.0f / l_run;
    float* op = Og + base + (size_t)(q0 + l16) * DD + quad * 4;
#pragma unroll
    for (int mt = 0; mt < 4; ++mt) {
#pragma unroll
        for (int r = 0; r < 4; ++r)
            op[mt * 16 + r] = Ot[mt][r] * inv;
    }
}

// =====================================================================
// Fallback (no/short workspace): previous known-good fused kernel.
// =====================================================================
__global__ __launch_bounds__(512)
void fattn6(const float* __restrict__ Qg, const float* __restrict__ Kg,
            const float* __restrict__ Vg, const float* __restrict__ Mg,
            const float* __restrict__ Sg, float* __restrict__ Og)
{
    __shared__ __align__(16) f16_t Kh_lds[64][72];
    __shared__ __align__(16) f16_t Vt_lds[64][72];
    __shared__ __align__(16) f16_t Pt_lds[8][16][72];
    __shared__ float msk_lds[SS];

    const int bh   = blockIdx.x % BH;
    const int qt   = blockIdx.x / BH;
    const int b    = bh / HH;
    const int tid  = threadIdx.x;
    const int wave = tid >> 6;
    const int lane = tid & 63;
    const int l16  = lane & 15;
    const int quad = lane >> 4;

    const float sc = Sg[b] * 1.44269504088896340736f;
    const size_t base = (size_t)bh * SS * DD;
    const int q0 = qt * 128 + wave * 16;

    for (int i = tid; i < SS; i += 512) msk_lds[i] = Mg[(size_t)b * SS + i];

    f16x8 qf[2];
    {
        const float* qp = Qg + base + (size_t)(q0 + l16) * DD + quad * 8;
#pragma unroll
        for (int kc = 0; kc < 2; ++kc) {
            float4 a  = *(const float4*)(qp + kc * 32);
            float4 b4 = *(const float4*)(qp + kc * 32 + 4);
            f16x8 f;
            f[0] = (f16_t)(a.x * sc);  f[1] = (f16_t)(a.y * sc);
            f[2] = (f16_t)(a.z * sc);  f[3] = (f16_t)(a.w * sc);
            f[4] = (f16_t)(b4.x * sc); f[5] = (f16_t)(b4.y * sc);
            f[6] = (f16_t)(b4.z * sc); f[7] = (f16_t)(b4.w * sc);
            qf[kc] = f;
        }
    }

    f32x4 Ot[4];
#pragma unroll
    for (int mt = 0; mt < 4; ++mt) Ot[mt] = f32x4{0.f, 0.f, 0.f, 0.f};
    float m_run = -1e30f, l_run = 0.0f;

    const int krow = tid >> 3;
    const int kc8  = (tid & 7) * 8;
    const int vd   = tid & 63;
    const int vk0  = (tid >> 6) * 8;

    for (int kt = 0; kt < NT; ++kt) {
        __syncthreads();
        {
            const float* kp = Kg + base + (size_t)(kt * 64 + krow) * DD + kc8;
            float4 a0 = *(const float4*)(kp);
            float4 a1 = *(const float4*)(kp + 4);
            uint4 w = make_uint4(pkf16(a0.x, a0.y), pkf16(a0.z, a0.w),
                                 pkf16(a1.x, a1.y), pkf16(a1.z, a1.w));
            *(uint4*)&Kh_lds[krow][kc8] = w;
        }
        {
            const float* vp = Vg + base + (size_t)(kt * 64 + vk0) * DD + vd;
            const float* mp = &msk_lds[kt * 64 + vk0];
            float v0 = vp[0 * DD] * mp[0], v1 = vp[1 * DD] * mp[1];
            float v2 = vp[2 * DD] * mp[2], v3 = vp[3 * DD] * mp[3];
            float v4 = vp[4 * DD] * mp[4], v5 = vp[5 * DD] * mp[5];
            float v6 = vp[6 * DD] * mp[6], v7 = vp[7 * DD] * mp[7];
            uint4 w = make_uint4(pkf16(v0, v1), pkf16(v2, v3),
                                 pkf16(v4, v5), pkf16(v6, v7));
            *(uint4*)&Vt_lds[vd][vk0] = w;
        }
        __syncthreads();

        f32x4 Sfr[4];
#pragma unroll
        for (int mt = 0; mt < 4; ++mt) {
            f32x4 acc = f32x4{0.f, 0.f, 0.f, 0.f};
#pragma unroll
            for (int kc = 0; kc < 2; ++kc) {
                f16x8 kh = *(const f16x8*)&Kh_lds[mt * 16 + l16][kc * 32 + quad * 8];
                acc = __builtin_amdgcn_mfma_f32_16x16x32_f16(kh, qf[kc], acc, 0, 0, 0);
            }
            Sfr[mt] = acc;
        }

        float mx = Sfr[0][0];
#pragma unroll
        for (int mt = 0; mt < 4; ++mt)
#pragma unroll
            for (int r = 0; r < 4; ++r) mx = fmaxf(mx, Sfr[mt][r]);
        mx = fmaxf(mx, __shfl_xor(mx, 16));
        mx = fmaxf(mx, __shfl_xor(mx, 32));

        if (__any(mx > m_run)) {
            const float mnew  = fmaxf(m_run, mx);
            const float alpha = exp2f(m_run - mnew);
            m_run = mnew;
            l_run *= alpha;
#pragma unroll
            for (int mt = 0; mt < 4; ++mt) Ot[mt] *= alpha;
        }

        float ps[4][4];
        float rs = 0.0f;
#pragma unroll
        for (int mt = 0; mt < 4; ++mt)
#pragma unroll
            for (int r = 0; r < 4; ++r) {
                ps[mt][r] = exp2f(Sfr[mt][r] - m_run);
                rs += ps[mt][r];
            }
        rs += __shfl_xor(rs, 16);
        rs += __shfl_xor(rs, 32);
        l_run += rs;

#pragma unroll
        for (int mt = 0; mt < 4; ++mt) {
            uint2 w = make_uint2(pkf16(ps[mt][0], ps[mt][1]),
                                 pkf16(ps[mt][2], ps[mt][3]));
            *(uint2*)&Pt_lds[wave][l16][mt * 16 + quad * 4] = w;
        }

#pragma unroll
        for (int kc = 0; kc < 2; ++kc) {
            f16x8 pf = *(const f16x8*)&Pt_lds[wave][l16][kc * 32 + quad * 8];
#pragma unroll
            for (int mt = 0; mt < 4; ++mt) {
                f16x8 vf = *(const f16x8*)&Vt_lds[mt * 16 + l16][kc * 32 + quad * 8];
                Ot[mt] = __builtin_amdgcn_mfma_f32_16x16x32_f16(vf, pf, Ot[mt], 0, 0, 0);
            }
        }
    }

    const float inv = 1.0f / l_run;
    float* op = Og + base + (size_t)(q0 + l16) * DD + quad * 4;
#pragma unroll
    for (int mt = 0; mt < 4; ++mt) {
#pragma unroll
        for (int r = 0; r < 4; ++r)
            op[mt * 16 + r] = Ot[mt][r] * inv;
    }
}

extern "C" void kernel_launch(void* const* d_in, const int* in_sizes, int n_in,
                              void* d_out, int out_size, void* d_ws, size_t ws_size,
                              hipStream_t stream) {
    const float* Qg = (const float*)d_in[0];
    const float* Kg = (const float*)d_in[1];
    const float* Vg = (const float*)d_in[2];
    // d_in[3] = query_mask (all ones, unused by reference)
    const float* Mg = (const float*)d_in[4];  // key_mask [B,1,1,S]
    const float* Sg = (const float*)d_in[5];  // scale_factor [B,1,1,1]
    // d_in[6] = dropout (0, identity)
    float* Og = (float*)d_out;

    const size_t kv_elems = (size_t)BH * SS * DD;          // per array, f16
    const size_t need = 2 * kv_elems * sizeof(f16_t);      // 16.8 MB

    if (d_ws != nullptr && ws_size >= need) {
        f16_t* Kp = (f16_t*)d_ws;
        f16_t* Vp = Kp + kv_elems;
        prepack<<<dim3(BH * NT), dim3(256), 0, stream>>>(Kg, Vg, Mg, Kp, Vp);
        fattn8<<<dim3(BH * QB), dim3(512), 0, stream>>>(Qg, Kp, Vp, Sg, Og);
    } else {
        fattn6<<<dim3(BH * QB), dim3(512), 0, stream>>>(Qg, Kg, Vg, Mg, Sg, Og);
    }
}

// Round 4
// 146.636 us; speedup vs baseline: 1.1659x; 1.0547x over previous
//
#include <hip/hip_runtime.h>
#include <hip/hip_bf16.h>
#include <stdint.h>

// Problem constants: B=2, H=16, S=2048, D=64, fp32 in/out.
#define BB 2
#define HH 16
#define SS 2048
#define DD 64
constexpr int BH = BB * HH;
constexpr int NT = SS / 64;    // 32 K-tiles
constexpr int QB = 16;         // q-tiles of 128 => 16 blocks per bh

typedef _Float16 f16_t;
typedef f16_t f16x8 __attribute__((ext_vector_type(8)));
typedef float f32x4 __attribute__((ext_vector_type(4)));

__device__ __forceinline__ uint32_t pkf16(float a, float b) {
    // two fp32 -> packed f16x2 (v_cvt_pkrtz_f16_f32), as raw dword
    return __builtin_bit_cast(uint32_t, __builtin_amdgcn_cvt_pkrtz(a, b));
}
__device__ __forceinline__ float fmax3(float a, float b, float c) {
    return fmaxf(fmaxf(a, b), c);   // fuses to v_max3_f32
}

// =====================================================================
// Pre-pass: pack K -> f16 tiles [64 key][64 d], and V^T·mask -> f16 tiles
// [64 d][64 key], per (bh, kt).  Each row's eight 16B chunks are XOR-
// swizzled (chunk j -> j ^ (row&7)) IN GLOBAL MEMORY so the main kernel's
// linear global_load_lds image is already bank-conflict-free for the
// ds_read_b128 fragment reads.
// =====================================================================
__global__ __launch_bounds__(256)
void prepack(const float* __restrict__ Kg, const float* __restrict__ Vg,
             const float* __restrict__ Mg, f16_t* __restrict__ Kp,
             f16_t* __restrict__ Vp)
{
    __shared__ float Vs[64][65];          // fp32 V tile staging (+1 pad)
    const int bh = blockIdx.x % BH;
    const int kt = blockIdx.x / BH;
    const int b  = bh / HH;
    const int t  = threadIdx.x;
    const size_t gbase = (size_t)bh * SS * DD + (size_t)kt * 64 * DD;
    const size_t tbase = ((size_t)bh * NT + kt) * 4096;   // f16 elements

    // ---- K: 512 chunks of 16B (8 f16) ----
    for (int c = t; c < 512; c += 256) {
        const int row = c >> 3, j = c & 7;
        const float* kp = Kg + gbase + (size_t)row * DD + j * 8;
        float4 a = *(const float4*)kp;
        float4 d = *(const float4*)(kp + 4);
        uint4 w = make_uint4(pkf16(a.x, a.y), pkf16(a.z, a.w),
                             pkf16(d.x, d.y), pkf16(d.z, d.w));
        *(uint4*)&Kp[tbase + (size_t)row * 64 + ((j ^ (row & 7)) * 8)] = w;
    }

    // ---- V: coalesced fp32 load, mask fold, into LDS [key][d] ----
    for (int c = t; c < 1024; c += 256) {
        const int key = c >> 4, dc = (c & 15) * 4;
        float4 v = *(const float4*)(Vg + gbase + (size_t)key * DD + dc);
        const float m = Mg[(size_t)b * SS + kt * 64 + key];
        Vs[key][dc + 0] = v.x * m;
        Vs[key][dc + 1] = v.y * m;
        Vs[key][dc + 2] = v.z * m;
        Vs[key][dc + 3] = v.w * m;
    }
    __syncthreads();

    // ---- V^T: 512 chunks of 16B, transposed out of LDS ----
    for (int c = t; c < 512; c += 256) {
        const int dr = c >> 3, j = c & 7;
        float v0 = Vs[j * 8 + 0][dr], v1 = Vs[j * 8 + 1][dr];
        float v2 = Vs[j * 8 + 2][dr], v3 = Vs[j * 8 + 3][dr];
        float v4 = Vs[j * 8 + 4][dr], v5 = Vs[j * 8 + 5][dr];
        float v6 = Vs[j * 8 + 6][dr], v7 = Vs[j * 8 + 7][dr];
        uint4 w = make_uint4(pkf16(v0, v1), pkf16(v2, v3),
                             pkf16(v4, v5), pkf16(v6, v7));
        *(uint4*)&Vp[tbase + (size_t)dr * 64 + ((j ^ (dr & 7)) * 8)] = w;
    }
}

// =====================================================================
// Main kernel: flash attention over prepacked f16 tiles.
// Sync structure is EXACTLY round-2's (race-free across replay tripwires):
// K double-buffered, V triple-buffered, TWO barriers per K-tile, counted
// vmcnt(2) so the prefetch stays in flight across the top barrier.
// (Round-3's single-barrier variant raced on graph replays — reverted.)
// New vs round 2 (intra-wave only, deterministic):
// - Row sum via ones-MFMA: Osum = mfma(1, P, Osum) -> every lane gets the
//   full 64-key column sum (no sum tree, no sum shuffles, no l_run).
// - Shuffle-free max in the common case: __any(local_max > m+8) equals
//   the global check (OR across lanes == max); the 2 max shuffles move
//   inside the rare rescale branch.  Defer-max THR=8 keeps P <= 2^8.
// - fmax3 max tree (v_max3_f32), depth 3.
// =====================================================================
__global__ __launch_bounds__(512)
void fattn10(const float* __restrict__ Qg, const f16_t* __restrict__ Kp,
             const f16_t* __restrict__ Vp, const float* __restrict__ Sg,
             float* __restrict__ Og)
{
    __shared__ __align__(16) f16_t Kt[2][4096];          // 8KB per buffer
    __shared__ __align__(16) f16_t Vt[3][4096];          // triple buffer
    __shared__ __align__(16) f16_t Pt[8][16][72];        // per-wave P^T

    const int bh   = blockIdx.x % BH;      // bh-minor => XCD affinity
    const int qt   = blockIdx.x / BH;
    const int b    = bh / HH;
    const int tid  = threadIdx.x;
    const int wave = tid >> 6;
    const int lane = tid & 63;
    const int l16  = lane & 15;
    const int quad = lane >> 4;

    const float sc = Sg[b] * 1.44269504088896340736f;  // scale*log2e into Q
    const size_t base = (size_t)bh * SS * DD;
    const size_t tb0  = (size_t)bh * NT * 4096;        // f16 elems
    const int q0 = qt * 128 + wave * 16;

    // DMA-stage tile kt: each thread one 16B chunk of K and one of V.
    auto stage = [&](int kt, int kbuf, int vbuf) {
        const f16_t* ks = Kp + tb0 + (size_t)kt * 4096 + tid * 8;
        const f16_t* vs = Vp + tb0 + (size_t)kt * 4096 + tid * 8;
        __builtin_amdgcn_global_load_lds(
            (const __attribute__((address_space(1))) void*)ks,
            (__attribute__((address_space(3))) void*)&Kt[kbuf][wave * 512],
            16, 0, 0);
        __builtin_amdgcn_global_load_lds(
            (const __attribute__((address_space(1))) void*)vs,
            (__attribute__((address_space(3))) void*)&Vt[vbuf][wave * 512],
            16, 0, 0);
    };

    stage(0, 0, 0);   // prefetch tile 0 before anything else

    // ---- Q fragments (B-operand layout), fp16 of (q * sc) ----
    f16x8 qf[2];
    {
        const float* qp = Qg + base + (size_t)(q0 + l16) * DD + quad * 8;
#pragma unroll
        for (int kc = 0; kc < 2; ++kc) {
            float4 a  = *(const float4*)(qp + kc * 32);
            float4 b4 = *(const float4*)(qp + kc * 32 + 4);
            f16x8 f;
            f[0] = (f16_t)(a.x * sc);  f[1] = (f16_t)(a.y * sc);
            f[2] = (f16_t)(a.z * sc);  f[3] = (f16_t)(a.w * sc);
            f[4] = (f16_t)(b4.x * sc); f[5] = (f16_t)(b4.y * sc);
            f[6] = (f16_t)(b4.z * sc); f[7] = (f16_t)(b4.w * sc);
            qf[kc] = f;
        }
    }

    f16x8 ones;
#pragma unroll
    for (int i = 0; i < 8; ++i) ones[i] = (f16_t)1.0f;

    f32x4 Ot[4];                // O^T: D[m=d=mt*16+quad*4+r][n=q=l16]
#pragma unroll
    for (int mt = 0; mt < 4; ++mt) Ot[mt] = f32x4{0.f, 0.f, 0.f, 0.f};
    f32x4 Osum = f32x4{0.f, 0.f, 0.f, 0.f};   // all rows = sum_k P^T[k][q]
    float m_run = -1e30f;

    const int swz = (l16 & 7) << 3;   // f16-index XOR within a 64-elem row

    int vcur = 0;                     // kt % 3
    for (int kt = 0; kt < NT; ++kt) {
        const int kcur = kt & 1;
        const int vnxt = (vcur == 2) ? 0 : vcur + 1;
        if (kt + 1 < NT) {
            stage(kt + 1, kcur ^ 1, vnxt);            // prefetch next tile
            asm volatile("s_waitcnt vmcnt(2)" ::: "memory");  // tile kt done
        } else {
            asm volatile("s_waitcnt vmcnt(0)" ::: "memory");
        }
        __builtin_amdgcn_s_barrier();   // tile kt visible to all waves

        __builtin_amdgcn_s_setprio(1);
        // ---- S^T = K Q^T  (tile kt) ----
        f32x4 Sfr[4];
#pragma unroll
        for (int mt = 0; mt < 4; ++mt) {
            f32x4 acc = f32x4{0.f, 0.f, 0.f, 0.f};
#pragma unroll
            for (int kc = 0; kc < 2; ++kc) {
                const int off = (mt * 16 + l16) * 64 + ((kc * 32 + quad * 8) ^ swz);
                f16x8 kh = *(const f16x8*)&Kt[kcur][off];
                acc = __builtin_amdgcn_mfma_f32_16x16x32_f16(kh, qf[kc], acc, 0, 0, 0);
            }
            Sfr[mt] = acc;   // D[m=key][n=q=l16], pre-scaled (sc in Q)
        }

        // ---- O^T += V^T(kt-1) P^T(kt-1); Osum += 1·P^T(kt-1) ----
        if (kt > 0) {
            const int vprv = (vcur == 0) ? 2 : vcur - 1;
#pragma unroll
            for (int kc = 0; kc < 2; ++kc) {
                f16x8 pf = *(const f16x8*)&Pt[wave][l16][kc * 32 + quad * 8];
#pragma unroll
                for (int mt = 0; mt < 4; ++mt) {
                    const int off = (mt * 16 + l16) * 64 + ((kc * 32 + quad * 8) ^ swz);
                    f16x8 vf = *(const f16x8*)&Vt[vprv][off];
                    Ot[mt] = __builtin_amdgcn_mfma_f32_16x16x32_f16(vf, pf, Ot[mt], 0, 0, 0);
                }
                Osum = __builtin_amdgcn_mfma_f32_16x16x32_f16(ones, pf, Osum, 0, 0, 0);
            }
        }
        __builtin_amdgcn_s_setprio(0);

        // ---- Online softmax (tile kt): 16 in-lane values (q = l16) ----
        float g0 = fmax3(Sfr[0][0], Sfr[0][1], Sfr[0][2]);
        float g1 = fmax3(Sfr[0][3], Sfr[1][0], Sfr[1][1]);
        float g2 = fmax3(Sfr[1][2], Sfr[1][3], Sfr[2][0]);
        float g3 = fmax3(Sfr[2][1], Sfr[2][2], Sfr[2][3]);
        float g4 = fmax3(Sfr[3][0], Sfr[3][1], Sfr[3][2]);
        float h0 = fmax3(g0, g1, Sfr[3][3]);
        float h1 = fmax3(g2, g3, g4);
        const float lmax = fmaxf(h0, h1);   // lane-local (16 keys) max

        // __any over lanes == "some q-column max exceeds m+8" (OR == max).
        if (__any(lmax > m_run + 8.0f)) {
            float mxq = fmaxf(lmax, __shfl_xor(lmax, 16));
            mxq = fmaxf(mxq, __shfl_xor(mxq, 32));     // per-q global max
            const float mnew  = fmaxf(m_run, mxq);
            const float alpha = __builtin_amdgcn_exp2f(m_run - mnew);
            m_run = mnew;
#pragma unroll
            for (int mt = 0; mt < 4; ++mt) Ot[mt] *= alpha;
            Osum *= alpha;
        }

        float ps[4][4];
#pragma unroll
        for (int mt = 0; mt < 4; ++mt)
#pragma unroll
            for (int r = 0; r < 4; ++r)
                ps[mt][r] = __builtin_amdgcn_exp2f(Sfr[mt][r] - m_run);

        // ---- P^T(kt) -> LDS (read by PV next iteration; same wave) ----
#pragma unroll
        for (int mt = 0; mt < 4; ++mt) {
            uint2 w = make_uint2(pkf16(ps[mt][0], ps[mt][1]),
                                 pkf16(ps[mt][2], ps[mt][3]));
            *(uint2*)&Pt[wave][l16][mt * 16 + quad * 4] = w;
        }

        __builtin_amdgcn_s_barrier();   // reads of K[kcur]/V[vprv] done
        vcur = vnxt;
    }

    // ---- Drain: PV(NT-1) + Osum(NT-1) ----
    {
        const int vprv = (vcur == 0) ? 2 : vcur - 1;   // (NT-1) % 3
#pragma unroll
        for (int kc = 0; kc < 2; ++kc) {
            f16x8 pf = *(const f16x8*)&Pt[wave][l16][kc * 32 + quad * 8];
#pragma unroll
            for (int mt = 0; mt < 4; ++mt) {
                const int off = (mt * 16 + l16) * 64 + ((kc * 32 + quad * 8) ^ swz);
                f16x8 vf = *(const f16x8*)&Vt[vprv][off];
                Ot[mt] = __builtin_amdgcn_mfma_f32_16x16x32_f16(vf, pf, Ot[mt], 0, 0, 0);
            }
            Osum = __builtin_amdgcn_mfma_f32_16x16x32_f16(ones, pf, Osum, 0, 0, 0);
        }
    }

    // ---- Epilogue: O[q][d] = O^T[d][q] / l   (l = Osum, any row) ----
    const float inv = 1.0f / Osum[0];
    float* op = Og + base + (size_t)(q0 + l16) * DD + quad * 4;
#pragma unroll
    for (int mt = 0; mt < 4; ++mt) {
#pragma unroll
        for (int r = 0; r < 4; ++r)
            op[mt * 16 + r] = Ot[mt][r] * inv;
    }
}

// =====================================================================
// Fallback (no/short workspace): previous known-good fused kernel.
// =====================================================================
__global__ __launch_bounds__(512)
void fattn6(const float* __restrict__ Qg, const float* __restrict__ Kg,
            const float* __restrict__ Vg, const float* __restrict__ Mg,
            const float* __restrict__ Sg, float* __restrict__ Og)
{
    __shared__ __align__(16) f16_t Kh_lds[64][72];
    __shared__ __align__(16) f16_t Vt_lds[64][72];
    __shared__ __align__(16) f16_t Pt_lds[8][16][72];
    __shared__ float msk_lds[SS];

    const int bh   = blockIdx.x % BH;
    const int qt   = blockIdx.x / BH;
    const int b    = bh / HH;
    const int tid  = threadIdx.x;
    const int wave = tid >> 6;
    const int lane = tid & 63;
    const int l16  = lane & 15;
    const int quad = lane >> 4;

    const float sc = Sg[b] * 1.44269504088896340736f;
    const size_t base = (size_t)bh * SS * DD;
    const int q0 = qt * 128 + wave * 16;

    for (int i = tid; i < SS; i += 512) msk_lds[i] = Mg[(size_t)b * SS + i];

    f16x8 qf[2];
    {
        const float* qp = Qg + base + (size_t)(q0 + l16) * DD + quad * 8;
#pragma unroll
        for (int kc = 0; kc < 2; ++kc) {
            float4 a  = *(const float4*)(qp + kc * 32);
            float4 b4 = *(const float4*)(qp + kc * 32 + 4);
            f16x8 f;
            f[0] = (f16_t)(a.x * sc);  f[1] = (f16_t)(a.y * sc);
            f[2] = (f16_t)(a.z * sc);  f[3] = (f16_t)(a.w * sc);
            f[4] = (f16_t)(b4.x * sc); f[5] = (f16_t)(b4.y * sc);
            f[6] = (f16_t)(b4.z * sc); f[7] = (f16_t)(b4.w * sc);
            qf[kc] = f;
        }
    }

    f32x4 Ot[4];
#pragma unroll
    for (int mt = 0; mt < 4; ++mt) Ot[mt] = f32x4{0.f, 0.f, 0.f, 0.f};
    float m_run = -1e30f, l_run = 0.0f;

    const int krow = tid >> 3;
    const int kc8  = (tid & 7) * 8;
    const int vd   = tid & 63;
    const int vk0  = (tid >> 6) * 8;

    for (int kt = 0; kt < NT; ++kt) {
        __syncthreads();
        {
            const float* kp = Kg + base + (size_t)(kt * 64 + krow) * DD + kc8;
            float4 a0 = *(const float4*)(kp);
            float4 a1 = *(const float4*)(kp + 4);
            uint4 w = make_uint4(pkf16(a0.x, a0.y), pkf16(a0.z, a0.w),
                                 pkf16(a1.x, a1.y), pkf16(a1.z, a1.w));
            *(uint4*)&Kh_lds[krow][kc8] = w;
        }
        {
            const float* vp = Vg + base + (size_t)(kt * 64 + vk0) * DD + vd;
            const float* mp = &msk_lds[kt * 64 + vk0];
            float v0 = vp[0 * DD] * mp[0], v1 = vp[1 * DD] * mp[1];
            float v2 = vp[2 * DD] * mp[2], v3 = vp[3 * DD] * mp[3];
            float v4 = vp[4 * DD] * mp[4], v5 = vp[5 * DD] * mp[5];
            float v6 = vp[6 * DD] * mp[6], v7 = vp[7 * DD] * mp[7];
            uint4 w = make_uint4(pkf16(v0, v1), pkf16(v2, v3),
                                 pkf16(v4, v5), pkf16(v6, v7));
            *(uint4*)&Vt_lds[vd][vk0] = w;
        }
        __syncthreads();

        f32x4 Sfr[4];
#pragma unroll
        for (int mt = 0; mt < 4; ++mt) {
            f32x4 acc = f32x4{0.f, 0.f, 0.f, 0.f};
#pragma unroll
            for (int kc = 0; kc < 2; ++kc) {
                f16x8 kh = *(const f16x8*)&Kh_lds[mt * 16 + l16][kc * 32 + quad * 8];
                acc = __builtin_amdgcn_mfma_f32_16x16x32_f16(kh, qf[kc], acc, 0, 0, 0);
            }
            Sfr[mt] = acc;
        }

        float mx = Sfr[0][0];
#pragma unroll
        for (int mt = 0; mt < 4; ++mt)
#pragma unroll
            for (int r = 0; r < 4; ++r) mx = fmaxf(mx, Sfr[mt][r]);
        mx = fmaxf(mx, __shfl_xor(mx, 16));
        mx = fmaxf(mx, __shfl_xor(mx, 32));

        if (__any(mx > m_run)) {
            const float mnew  = fmaxf(m_run, mx);
            const float alpha = exp2f(m_run - mnew);
            m_run = mnew;
            l_run *= alpha;
#pragma unroll
            for (int mt = 0; mt < 4; ++mt) Ot[mt] *= alpha;
        }

        float ps[4][4];
        float rs = 0.0f;
#pragma unroll
        for (int mt = 0; mt < 4; ++mt)
#pragma unroll
            for (int r = 0; r < 4; ++r) {
                ps[mt][r] = exp2f(Sfr[mt][r] - m_run);
                rs += ps[mt][r];
            }
        rs += __shfl_xor(rs, 16);
        rs += __shfl_xor(rs, 32);
        l_run += rs;

#pragma unroll
        for (int mt = 0; mt < 4; ++mt) {
            uint2 w = make_uint2(pkf16(ps[mt][0], ps[mt][1]),
                                 pkf16(ps[mt][2], ps[mt][3]));
            *(uint2*)&Pt_lds[wave][l16][mt * 16 + quad * 4] = w;
        }

#pragma unroll
        for (int kc = 0; kc < 2; ++kc) {
            f16x8 pf = *(const f16x8*)&Pt_lds[wave][l16][kc * 32 + quad * 8];
#pragma unroll
            for (int mt = 0; mt < 4; ++mt) {
                f16x8 vf = *(const f16x8*)&Vt_lds[mt * 16 + l16][kc * 32 + quad * 8];
                Ot[mt] = __builtin_amdgcn_mfma_f32_16x16x32_f16(vf, pf, Ot[mt], 0, 0, 0);
            }
        }
    }

    const float inv = 1.0f / l_run;
    float* op = Og + base + (size_t)(q0 + l16) * DD + quad * 4;
#pragma unroll
    for (int mt = 0; mt < 4; ++mt) {
#pragma unroll
        for (int r = 0; r < 4; ++r)
            op[mt * 16 + r] = Ot[mt][r] * inv;
    }
}

extern "C" void kernel_launch(void* const* d_in, const int* in_sizes, int n_in,
                              void* d_out, int out_size, void* d_ws, size_t ws_size,
                              hipStream_t stream) {
    const float* Qg = (const float*)d_in[0];
    const float* Kg = (const float*)d_in[1];
    const float* Vg = (const float*)d_in[2];
    // d_in[3] = query_mask (all ones, unused by reference)
    const float* Mg = (const float*)d_in[4];  // key_mask [B,1,1,S]
    const float* Sg = (const float*)d_in[5];  // scale_factor [B,1,1,1]
    // d_in[6] = dropout (0, identity)
    float* Og = (float*)d_out;

    const size_t kv_elems = (size_t)BH * SS * DD;          // per array, f16
    const size_t need = 2 * kv_elems * sizeof(f16_t);      // 16.8 MB

    if (d_ws != nullptr && ws_size >= need) {
        f16_t* Kp = (f16_t*)d_ws;
        f16_t* Vp = Kp + kv_elems;
        prepack<<<dim3(BH * NT), dim3(256), 0, stream>>>(Kg, Vg, Mg, Kp, Vp);
        fattn10<<<dim3(BH * QB), dim3(512), 0, stream>>>(Qg, Kp, Vp, Sg, Og);
    } else {
        fattn6<<<dim3(BH * QB), dim3(512), 0, stream>>>(Qg, Kg, Vg, Mg, Sg, Og);
    }
}